// Round 14
// baseline (32.172 us; speedup 1.0000x reference)
//
#include <hip/hip_runtime.h>

// Retrace loss: T=8192, K=2048, gamma=0.99.
// decay = cumprod(gamma*iw); S = reverse-cumsum(td*decay);
// retrace = S / max(decay,1e-10); loss = mean(smooth_l1(q, retrace)).
//
// f32 decay underflows to EXACT 0 fast (E[ln c]=-0.574, sd 0.83/step; at
// row 384 log-decay = -220 +- 16.3 vs f32 denorm floor ~-103 => alive
// needs +7.2 sigma, P ~ 6e-10 over all columns; c<=0.99 is monotone so
// any association order underflows together). Once decay==0, retrace==0
// in both our and the reference's arithmetic (absmax 0.0, rounds 6-13).
// Role C is the exact per-column fallback if a column ever survives.
//
// Structure lessons (hard-won):
//  R7 : 64-round latency chain co-scheduled with a BW flood stretches 5x.
//  R8 : __threadfence ticket in a wide grid = L2 writeback storm (448us).
//  R9 : single-address f64 atomics + shared ctrl cacheline = 50us.
//  R10-R12: zero-atomic partials; time tracks LAUNCH COUNT; 3 launches=31us.
//  R13: register-only kPre (32 indep loads -> ONE wait -> chain) = 27.9us.
//  R14: tail flood moved INTO launch 1 next to kPre -- safe now because
//       kPre has ONE load round-trip (vs R7's 64), so the flood can't
//       stretch a serial chain. kApply shrinks to roles A+C (L2-hot).

#define GAMMA 0.99f

constexpr int T_ = 8192;
constexpr int K_ = 2048;
constexpr int N_ = T_ - 1;               // 8191
constexpr int MROWS = 384;               // exact-prefix length
constexpr int L_ = 8;                    // rows per chunk
constexpr int MCH = MROWS / L_;          // 48 chunks
constexpr int NBPRE = MCH * (K_ / 256);  // 384 blocks (kPre work / role A)
constexpr int NBTAIL = 2048;             // tail blocks (in launch 1)
constexpr int NBC = K_ / 256;            // 8 role-C blocks
constexpr int NB1 = NBPRE + NBTAIL;      // 2432 blocks, launch 1
constexpr int NB2 = NBPRE + NBC;         // 392 blocks, launch 2
constexpr int NPART = NBTAIL + NB2;      // 2440 partials slots
constexpr long long TAILF4 = (long long)(N_ - MROWS) * K_ / 4;  // 3,997,184

typedef float f4 __attribute__((ext_vector_type(4)));

__device__ __forceinline__ unsigned short f2bf(float f) {  // RTNE
  unsigned u = __float_as_uint(f);
  u += 0x7FFFu + ((u >> 16) & 1u);
  return (unsigned short)(u >> 16);
}
__device__ __forceinline__ float bf2f(unsigned short h) {
  return __uint_as_float(((unsigned)h) << 16);
}
__device__ __forceinline__ float bfhi(unsigned q) {  // y in hi16
  return __uint_as_float(q & 0xFFFF0000u);
}
__device__ __forceinline__ float bflo(unsigned q) {  // ld in lo16
  return __uint_as_float(q << 16);
}
__device__ __forceinline__ float sl1(float dd) {
  float ad = fabsf(dd);
  return (ad < 1.f) ? 0.5f * dd * dd : ad - 0.5f;
}
// Block sum -> slot (plain store, no atomics).
__device__ __forceinline__ void block_reduce_store(float l, float* slot) {
  for (int off = 32; off > 0; off >>= 1) l += __shfl_down(l, off);
  __shared__ float wsum[4];
  const int lane = threadIdx.x & 63, wid = threadIdx.x >> 6;
  if (lane == 0) wsum[wid] = l;
  __syncthreads();
  if (threadIdx.x == 0) *slot = wsum[0] + wsum[1] + wsum[2] + wsum[3];
}

// ---------------------------------------------------------------- k1
// Blocks [0,NBPRE): register-only prefix chain (R13 kPre, unchanged).
// Blocks [NBPRE,NB1): unconditional tail sum sl1(sv) -> partials[0..2047].
__global__ __launch_bounds__(256) void k1(
    const float* __restrict__ sv, const float* __restrict__ tsv,
    const float* __restrict__ tev, const float* __restrict__ r,
    const float* __restrict__ ologp, const float* __restrict__ tlogp,
    unsigned* __restrict__ pkPre, float* __restrict__ P,
    float* __restrict__ Zl, float* __restrict__ partials) {
  const int bid = blockIdx.x;
  const int tid = threadIdx.x;

  if (bid < NBPRE) {  // ---- prefix chain: thread = (chunk, col)
    const int chunk = bid >> 3;
    const int k = (bid & 7) * 256 + tid;
    const int i0 = chunk * L_;
    float lw[L_], a[L_], v[L_], rr[L_], o[L_];
#pragma unroll
    for (int s = 0; s < L_; ++s) {  // all loads independent -> one wait
      const int i = i0 + s;
      const size_t b1 = (size_t)(i + 1) * K_ + k;
      lw[s] = tlogp[b1];
      a[s] = tsv[b1];
      v[s] = tev[b1];
      rr[s] = r[(size_t)i * K_ + k];
      o[s] = ologp[i + 1];  // block-uniform -> scalar load
    }
    float p = 1.f, zl = 0.f;
#pragma unroll
    for (int s = 0; s < L_; ++s) {
      float iw = __expf(fminf(lw[s] - o[s], 0.f));
      float c = GAMMA * iw;
      p *= c;
      float td = fmaf(GAMMA, fmaf(-iw, a[s], v[s]), rr[s]);
      float tdb = bf2f(f2bf(td));  // bf16 round-trip (proven path)
      float y = tdb * p;
      zl += y;
      pkPre[(size_t)(i0 + s) * K_ + k] = ((unsigned)f2bf(y) << 16) | f2bf(p);
    }
    P[(size_t)chunk * K_ + k] = p;
    Zl[(size_t)chunk * K_ + k] = zl;
  } else {  // ---- tail rows [MROWS,N): unconditional sl1(sv)
    const long long base = (long long)MROWS * K_ / 4;  // f4 offset
    float loss = 0.f;
    for (long long v = (long long)(bid - NBPRE) * 256 + tid; v < TAILF4;
         v += (long long)NBTAIL * 256) {
      f4 q = ((const f4*)sv)[base + v];
#pragma unroll
      for (int x = 0; x < 4; ++x) loss += sl1(q[x]);
    }
    block_reduce_store(loss, partials + (bid - NBPRE));
  }
}

// ---------------------------------------------------------------- k2
// Role A [0,NBPRE): prefix apply with inline chunk scan over P/Zl
//   (L2-hot; forward-order ssuf proven R7/R12, absmax 0.0).
// Role C [NBPRE,NB2): thread per column, inline alive check; exact
//   serial fallback (subtracts the tail terms k1 assumed; never taken
//   for this data). partials offset by NBTAIL.
__global__ __launch_bounds__(256) void k2(
    const float* __restrict__ sv, const float* __restrict__ tsv,
    const float* __restrict__ tev, const float* __restrict__ r,
    const float* __restrict__ ologp, const float* __restrict__ tlogp,
    const unsigned* __restrict__ pkPre, const float* __restrict__ P,
    const float* __restrict__ Zl, unsigned* __restrict__ pkFull,
    float* __restrict__ partials) {
  const int bid = blockIdx.x;
  const int tid = threadIdx.x;

  if (bid < NBPRE) {  // ---- role A: prefix rows [0,MROWS)
    const int myc = bid >> 3;
    const int k = (bid & 7) * 256 + tid;
    float d0 = 1.f, dj = 1.f;
#pragma unroll 16
    for (int c = 0; c < MCH; ++c) {
      if (c == myc) d0 = dj;
      dj *= P[(size_t)c * K_ + k];
    }
    float loss = 0.f;
    if (dj == 0.f) {  // dead column (typical): chunked result is exact
      float ssuf = 0.f;
      float dp = d0 * P[(size_t)myc * K_ + k];
      for (int c = myc + 1; c < MCH; ++c) {
        ssuf = fmaf(dp, Zl[(size_t)c * K_ + k], ssuf);
        dp *= P[(size_t)c * K_ + k];
      }
      const int i0 = myc * L_;
      float slocal = 0.f;
#pragma unroll
      for (int s = L_ - 1; s >= 0; --s) {
        const size_t b0 = (size_t)(i0 + s) * K_ + k;
        unsigned q = pkPre[b0];
        slocal += bfhi(q);
        float S = fmaf(d0, slocal, ssuf);
        float retrace = S / fmaxf(d0 * bflo(q), 1e-10f);
        loss += sl1(sv[b0] - retrace);
      }
    }
    block_reduce_store(loss, partials + NBTAIL + bid);
  } else {  // ---- role C: thread per column; inline alive check
    const int k = (bid - NBPRE) * 256 + tid;
    float loss = 0.f;
    float dj = 1.f;
#pragma unroll 16
    for (int c = 0; c < MCH; ++c) dj *= P[(size_t)c * K_ + k];
    if (dj != 0.f) {  // alive (never for this data): exact recompute
      unsigned* mycol = pkFull + (size_t)k * 8192;
      float p = 1.f;
      for (int i = 0; i < N_; ++i) {  // forward: exact sequential decay
        const size_t b1 = (size_t)(i + 1) * K_ + k;
        float iw = __expf(fminf(tlogp[b1] - ologp[i + 1], 0.f));
        p *= GAMMA * iw;
        float td =
            fmaf(GAMMA, fmaf(-iw, tsv[b1], tev[b1]), r[(size_t)i * K_ + k]);
        mycol[i] = ((unsigned)f2bf(td * p) << 16) | f2bf(p);
      }
      float slocal = 0.f;
      for (int i = N_ - 1; i >= 0; --i) {  // backward: S, loss, tail undo
        unsigned q = mycol[i];
        slocal += bfhi(q);
        float retrace = slocal / fmaxf(bflo(q), 1e-10f);
        float qv = sv[(size_t)i * K_ + k];
        loss += sl1(qv - retrace);
        if (i >= MROWS) loss -= sl1(qv);  // k1 tail added this for ALL cols
      }
      // role A contributed 0 for alive columns (dj != 0 skip) -> no dup.
    }
    block_reduce_store(loss, partials + NBTAIL + bid);
  }
}

// ---------------------------------------------------------------- k4
// Single block: f64 sum of the 2440 per-block partials, write mean.
__global__ __launch_bounds__(256) void k4(const float* __restrict__ partials,
                                          float* __restrict__ out) {
  double d = 0.0;
  for (int i = threadIdx.x; i < NPART; i += 256) d += (double)partials[i];
  for (int off = 32; off > 0; off >>= 1) d += __shfl_down(d, off);
  __shared__ double wsum[4];
  const int lane = threadIdx.x & 63, wid = threadIdx.x >> 6;
  if (lane == 0) wsum[wid] = d;
  __syncthreads();
  if (threadIdx.x == 0) {
    double s = wsum[0] + wsum[1] + wsum[2] + wsum[3];
    out[0] = (float)(s * (1.0 / ((double)N_ * (double)K_)));
  }
}

extern "C" void kernel_launch(void* const* d_in, const int* in_sizes, int n_in,
                              void* d_out, int out_size, void* d_ws,
                              size_t ws_size, hipStream_t stream) {
  const float* sv = (const float*)d_in[0];
  const float* tsv = (const float*)d_in[1];
  const float* tev = (const float*)d_in[2];
  const float* r = (const float*)d_in[3];
  const float* ologp = (const float*)d_in[4];
  const float* tlogp = (const float*)d_in[5];

  // ws layout (~71 MB; harness provided >= 75.5 MB rounds 2-13).
  // partials on its own page (R9 lesson: no ctrl-line sharing).
  char* w = (char*)d_ws;
  float* partials = (float*)w;  // 2440 f32, page 0
  w += 16384;
  unsigned* pkPre = (unsigned*)w;  // 384*2048*4 = 3 MB
  w += (size_t)MROWS * K_ * 4;
  float* P = (float*)w;  // 48*2048*4 = 384 KB each
  w += (size_t)MCH * K_ * 4;
  float* Zl = (float*)w;
  w += (size_t)MCH * K_ * 4;
  unsigned* pkFull = (unsigned*)w;  // 67 MB (role-C fallback only)

  k1<<<NB1, 256, 0, stream>>>(sv, tsv, tev, r, ologp, tlogp, pkPre, P, Zl,
                              partials);
  k2<<<NB2, 256, 0, stream>>>(sv, tsv, tev, r, ologp, tlogp, pkPre, P, Zl,
                              pkFull, partials);
  k4<<<1, 256, 0, stream>>>(partials, (float*)d_out);
}

// Round 15
// 28.818 us; speedup vs baseline: 1.1164x; 1.1164x over previous
//
#include <hip/hip_runtime.h>

// Retrace loss: T=8192, K=2048, gamma=0.99.
// decay = cumprod(gamma*iw); S = reverse-cumsum(td*decay);
// retrace = S / max(decay,1e-10); loss = mean(smooth_l1(q, retrace)).
//
// f32 decay underflows to EXACT 0 fast (E[ln c]=-0.574, sd 0.83/step; at
// row 384 log-decay = -220 +- 16.3 vs f32 denorm floor ~-103 => alive
// needs +7.2 sigma, P ~ 6e-10 over all columns). Once decay==0,
// retrace==0 in both our and the reference's arithmetic (absmax 0.0,
// rounds 6-14). Role C is the exact per-column fallback.
//
// Structure lessons (hard-won):
//  R7/R14: co-scheduling the prefix chain with the 63MB flood regresses
//          (5x at depth-64, +15% even at depth-1). NEVER mix them.
//  R8 : __threadfence ticket in a wide grid = L2 writeback storm (448us).
//  R9 : single-address f64 atomics + shared ctrl cacheline = 50us.
//  R10-R13: zero-atomic partials; time tracks LAUNCH COUNT; 3 launches +
//          register-only kPre = 27.9us (best).
//  R15: R13 + MLP-batched apply: role B = 16 independent f4 loads/thread
//       (Little's law: L3 at ~10TB/s x ~500ns wants ~10-16 16B loads in
//       flight per lane); role A batches pk/sv reads before the chain.

#define GAMMA 0.99f

constexpr int T_ = 8192;
constexpr int K_ = 2048;
constexpr int N_ = T_ - 1;               // 8191
constexpr int MROWS = 384;               // exact-prefix length
constexpr int L_ = 8;                    // rows per chunk
constexpr int MCH = MROWS / L_;          // 48 chunks
constexpr int NBPRE = MCH * (K_ / 256);  // 384 blocks (kPre and role A)
constexpr int NBTAIL = 1024;             // role-B blocks (batched x16)
constexpr int NBC = K_ / 256;            // 8 role-C blocks
constexpr int NBTOT = NBPRE + NBTAIL + NBC;  // 1416
constexpr long long TAILF4 = (long long)(N_ - MROWS) * K_ / 4;  // 3,997,184
constexpr int BTHR = NBTAIL * 256;           // 262,144 role-B threads
constexpr int BREM = (int)(TAILF4 - 15ll * BTHR);  // 65,024 (j=15 bound)

typedef float f4 __attribute__((ext_vector_type(4)));

__device__ __forceinline__ unsigned short f2bf(float f) {  // RTNE
  unsigned u = __float_as_uint(f);
  u += 0x7FFFu + ((u >> 16) & 1u);
  return (unsigned short)(u >> 16);
}
__device__ __forceinline__ float bf2f(unsigned short h) {
  return __uint_as_float(((unsigned)h) << 16);
}
__device__ __forceinline__ float bfhi(unsigned q) {  // y in hi16
  return __uint_as_float(q & 0xFFFF0000u);
}
__device__ __forceinline__ float bflo(unsigned q) {  // ld in lo16
  return __uint_as_float(q << 16);
}
__device__ __forceinline__ float sl1(float dd) {
  float ad = fabsf(dd);
  return (ad < 1.f) ? 0.5f * dd * dd : ad - 0.5f;
}
// Block sum -> partials[bid] (plain store, no atomics).
__device__ __forceinline__ void block_reduce_store(float l, float* slot) {
  for (int off = 32; off > 0; off >>= 1) l += __shfl_down(l, off);
  __shared__ float wsum[4];
  const int lane = threadIdx.x & 63, wid = threadIdx.x >> 6;
  if (lane == 0) wsum[wid] = l;
  __syncthreads();
  if (threadIdx.x == 0) *slot = wsum[0] + wsum[1] + wsum[2] + wsum[3];
}

// ---------------------------------------------------------------- kPre
// Register-only (R13, proven): thread = (chunk, col); 32 independent
// coalesced loads -> one wait -> f32 chain; packed bf16 (y|ld) store.
__global__ __launch_bounds__(256) void kPre(
    const float* __restrict__ tsv, const float* __restrict__ tev,
    const float* __restrict__ r, const float* __restrict__ ologp,
    const float* __restrict__ tlogp, unsigned* __restrict__ pkPre,
    float* __restrict__ P, float* __restrict__ Zl) {
  const int chunk = blockIdx.x >> 3;  // 0..MCH-1
  const int k = (blockIdx.x & 7) * 256 + threadIdx.x;
  const int i0 = chunk * L_;

  float lw[L_], a[L_], v[L_], rr[L_], o[L_];
#pragma unroll
  for (int s = 0; s < L_; ++s) {  // all loads independent -> MLP
    const int i = i0 + s;
    const size_t b1 = (size_t)(i + 1) * K_ + k;
    lw[s] = tlogp[b1];
    a[s] = tsv[b1];
    v[s] = tev[b1];
    rr[s] = r[(size_t)i * K_ + k];
    o[s] = ologp[i + 1];  // block-uniform -> scalar load
  }
  float p = 1.f, zl = 0.f;
#pragma unroll
  for (int s = 0; s < L_; ++s) {
    float iw = __expf(fminf(lw[s] - o[s], 0.f));
    float c = GAMMA * iw;
    p *= c;
    float td = fmaf(GAMMA, fmaf(-iw, a[s], v[s]), rr[s]);
    float tdb = bf2f(f2bf(td));  // bf16 round-trip (proven path)
    float y = tdb * p;
    zl += y;
    pkPre[(size_t)(i0 + s) * K_ + k] = ((unsigned)f2bf(y) << 16) | f2bf(p);
  }
  P[(size_t)chunk * K_ + k] = p;
  Zl[(size_t)chunk * K_ + k] = zl;
}

// ---------------------------------------------------------------- kApply
// Role A: prefix apply, inline chunk scan (R12-proven), batched loads.
// Role B: tail sl1(sv) unconditional, 16 independent f4 loads/thread.
// Role C: inline alive check; exact serial fallback (never for this data).
// Every block writes its own partials slot. NO atomics, NO fences.
__global__ __launch_bounds__(256) void kApply(
    const float* __restrict__ sv, const float* __restrict__ tsv,
    const float* __restrict__ tev, const float* __restrict__ r,
    const float* __restrict__ ologp, const float* __restrict__ tlogp,
    const unsigned* __restrict__ pkPre, const float* __restrict__ P,
    const float* __restrict__ Zl, unsigned* __restrict__ pkFull,
    float* __restrict__ partials) {
  const int bid = blockIdx.x;
  const int tid = threadIdx.x;

  if (bid < NBPRE) {  // ---- role A: prefix rows [0,MROWS)
    const int myc = bid >> 3;
    const int k = (bid & 7) * 256 + tid;
    float d0 = 1.f, dj = 1.f;
#pragma unroll 16
    for (int c = 0; c < MCH; ++c) {
      if (c == myc) d0 = dj;
      dj *= P[(size_t)c * K_ + k];
    }
    float loss = 0.f;
    if (dj == 0.f) {  // dead column (typical): chunked result is exact
      float ssuf = 0.f;
      float dp = d0 * P[(size_t)myc * K_ + k];
      for (int c = myc + 1; c < MCH; ++c) {
        ssuf = fmaf(dp, Zl[(size_t)c * K_ + k], ssuf);
        dp *= P[(size_t)c * K_ + k];
      }
      const int i0 = myc * L_;
      unsigned q[L_];
      float svv[L_];
#pragma unroll
      for (int s = 0; s < L_; ++s) {  // batch loads before the chain
        const size_t b0 = (size_t)(i0 + s) * K_ + k;
        q[s] = pkPre[b0];
        svv[s] = sv[b0];
      }
      float slocal = 0.f;
#pragma unroll
      for (int s = L_ - 1; s >= 0; --s) {
        slocal += bfhi(q[s]);
        float S = fmaf(d0, slocal, ssuf);
        float retrace = S / fmaxf(d0 * bflo(q[s]), 1e-10f);
        loss += sl1(svv[s] - retrace);
      }
    }
    block_reduce_store(loss, partials + bid);
  } else if (bid < NBPRE + NBTAIL) {  // ---- role B: tail, batched x16
    const int t = (bid - NBPRE) * 256 + tid;  // 0..BTHR-1
    const f4* sv4 = (const f4*)sv + (long long)MROWS * K_ / 4;
    f4 q[16];
#pragma unroll
    for (int j = 0; j < 15; ++j)  // 15 unconditional independent loads
      q[j] = sv4[(long long)t + (long long)j * BTHR];
    if (t < BREM) q[15] = sv4[(long long)t + 15ll * BTHR];
    else q[15] = f4{0.f, 0.f, 0.f, 0.f};  // sl1(0)=0
    float loss = 0.f;
#pragma unroll
    for (int j = 0; j < 16; ++j)
#pragma unroll
      for (int x = 0; x < 4; ++x) loss += sl1(q[j][x]);
    block_reduce_store(loss, partials + bid);
  } else {  // ---- role C: thread per column; inline alive check
    const int k = (bid - NBPRE - NBTAIL) * 256 + tid;
    float loss = 0.f;
    float dj = 1.f;
#pragma unroll 16
    for (int c = 0; c < MCH; ++c) dj *= P[(size_t)c * K_ + k];
    if (dj != 0.f) {  // alive (never for this data): exact recompute
      unsigned* mycol = pkFull + (size_t)k * 8192;
      float p = 1.f;
      for (int i = 0; i < N_; ++i) {  // forward: exact sequential decay
        const size_t b1 = (size_t)(i + 1) * K_ + k;
        float iw = __expf(fminf(tlogp[b1] - ologp[i + 1], 0.f));
        p *= GAMMA * iw;
        float td =
            fmaf(GAMMA, fmaf(-iw, tsv[b1], tev[b1]), r[(size_t)i * K_ + k]);
        mycol[i] = ((unsigned)f2bf(td * p) << 16) | f2bf(p);
      }
      float slocal = 0.f;
      for (int i = N_ - 1; i >= 0; --i) {  // backward: S, loss, tail undo
        unsigned q = mycol[i];
        slocal += bfhi(q);
        float retrace = slocal / fmaxf(bflo(q), 1e-10f);
        float qv = sv[(size_t)i * K_ + k];
        loss += sl1(qv - retrace);
        if (i >= MROWS) loss -= sl1(qv);  // role B added this for ALL cols
      }
      // role A contributed 0 for alive columns (dj != 0 skip) -> no dup.
    }
    block_reduce_store(loss, partials + bid);
  }
}

// ---------------------------------------------------------------- k4
// Single block: f64 sum of the 1416 per-block partials, write mean.
__global__ __launch_bounds__(256) void k4(const float* __restrict__ partials,
                                          float* __restrict__ out) {
  double d = 0.0;
  for (int i = threadIdx.x; i < NBTOT; i += 256) d += (double)partials[i];
  for (int off = 32; off > 0; off >>= 1) d += __shfl_down(d, off);
  __shared__ double wsum[4];
  const int lane = threadIdx.x & 63, wid = threadIdx.x >> 6;
  if (lane == 0) wsum[wid] = d;
  __syncthreads();
  if (threadIdx.x == 0) {
    double s = wsum[0] + wsum[1] + wsum[2] + wsum[3];
    out[0] = (float)(s * (1.0 / ((double)N_ * (double)K_)));
  }
}

extern "C" void kernel_launch(void* const* d_in, const int* in_sizes, int n_in,
                              void* d_out, int out_size, void* d_ws,
                              size_t ws_size, hipStream_t stream) {
  const float* sv = (const float*)d_in[0];
  const float* tsv = (const float*)d_in[1];
  const float* tev = (const float*)d_in[2];
  const float* r = (const float*)d_in[3];
  const float* ologp = (const float*)d_in[4];
  const float* tlogp = (const float*)d_in[5];

  // ws layout (~71 MB; harness provided >= 75.5 MB rounds 2-14).
  // partials on its own page (R9 lesson: no ctrl-line sharing).
  char* w = (char*)d_ws;
  float* partials = (float*)w;  // 1416 f32, page 0
  w += 16384;
  unsigned* pkPre = (unsigned*)w;  // 384*2048*4 = 3 MB
  w += (size_t)MROWS * K_ * 4;
  float* P = (float*)w;  // 48*2048*4 = 384 KB each
  w += (size_t)MCH * K_ * 4;
  float* Zl = (float*)w;
  w += (size_t)MCH * K_ * 4;
  unsigned* pkFull = (unsigned*)w;  // 67 MB (role-C fallback only)

  kPre<<<NBPRE, 256, 0, stream>>>(tsv, tev, r, ologp, tlogp, pkPre, P, Zl);
  kApply<<<NBTOT, 256, 0, stream>>>(sv, tsv, tev, r, ologp, tlogp, pkPre, P,
                                    Zl, pkFull, partials);
  k4<<<1, 256, 0, stream>>>(partials, (float*)d_out);
}

// Round 16
// 28.497 us; speedup vs baseline: 1.1289x; 1.0113x over previous
//
#include <hip/hip_runtime.h>

// Retrace loss: T=8192, K=2048, gamma=0.99.
// decay = cumprod(gamma*iw); S = reverse-cumsum(td*decay);
// retrace = S / max(decay,1e-10); loss = mean(smooth_l1(q, retrace)).
//
// f32 decay underflows to EXACT 0 fast (E[ln c]=-0.574, sd 0.83/step; at
// row 320 log-decay = -183.7 +- 14.85 vs f32 denorm floor ~-103.6 =>
// alive needs +5.4 sigma, P(any of 2048 cols) ~ 7e-5). Once decay==0,
// retrace==0 in both our and the reference's arithmetic (absmax 0.0,
// rounds 6-15). Role C is the exact per-column fallback if a column
// ever survives the prefix.
//
// Structure lessons (hard-won):
//  R7/R14: co-scheduling prefix work with the 63MB flood regresses
//          (5x at depth-64 chain, +15% even at depth-1). NEVER mix.
//  R8 : __threadfence ticket in a wide grid = L2 writeback storm (448us).
//       Also rules out cooperative grid.sync (same fence mechanism).
//  R9 : single-address f64 atomics + shared ctrl cacheline = 50us.
//  R15: 16-deep MLP batch on the tail flood = null -> role B is at the
//       L3/fabric bandwidth ceiling (~7 TB/s, matches fill kernels).
//  R10-R13: zero-atomic partials; time tracks LAUNCH COUNT; 3 launches +
//       register-only kPre = 27.9us (best). R16 = that + MROWS 384->320.

#define GAMMA 0.99f

constexpr int T_ = 8192;
constexpr int K_ = 2048;
constexpr int N_ = T_ - 1;               // 8191
constexpr int MROWS = 320;               // exact-prefix length
constexpr int L_ = 8;                    // rows per chunk
constexpr int MCH = MROWS / L_;          // 40 chunks
constexpr int NBPRE = MCH * (K_ / 256);  // 320 blocks (kPre and role A)
constexpr int NBTAIL = 2048;             // role-B blocks (rolled loop)
constexpr int NBC = K_ / 256;            // 8 role-C blocks
constexpr int NBTOT = NBPRE + NBTAIL + NBC;  // 2376
constexpr long long TAILF4 = (long long)(N_ - MROWS) * K_ / 4;  // 4,029,952

typedef float f4 __attribute__((ext_vector_type(4)));

__device__ __forceinline__ unsigned short f2bf(float f) {  // RTNE
  unsigned u = __float_as_uint(f);
  u += 0x7FFFu + ((u >> 16) & 1u);
  return (unsigned short)(u >> 16);
}
__device__ __forceinline__ float bf2f(unsigned short h) {
  return __uint_as_float(((unsigned)h) << 16);
}
__device__ __forceinline__ float bfhi(unsigned q) {  // y in hi16
  return __uint_as_float(q & 0xFFFF0000u);
}
__device__ __forceinline__ float bflo(unsigned q) {  // ld in lo16
  return __uint_as_float(q << 16);
}
__device__ __forceinline__ float sl1(float dd) {
  float ad = fabsf(dd);
  return (ad < 1.f) ? 0.5f * dd * dd : ad - 0.5f;
}
// Block sum -> partials[bid] (plain store, no atomics).
__device__ __forceinline__ void block_reduce_store(float l, float* slot) {
  for (int off = 32; off > 0; off >>= 1) l += __shfl_down(l, off);
  __shared__ float wsum[4];
  const int lane = threadIdx.x & 63, wid = threadIdx.x >> 6;
  if (lane == 0) wsum[wid] = l;
  __syncthreads();
  if (threadIdx.x == 0) *slot = wsum[0] + wsum[1] + wsum[2] + wsum[3];
}

// ---------------------------------------------------------------- kPre
// Register-only (R13, proven): thread = (chunk, col); 32 independent
// coalesced loads -> one wait -> f32 chain; packed bf16 (y|ld) store.
__global__ __launch_bounds__(256) void kPre(
    const float* __restrict__ tsv, const float* __restrict__ tev,
    const float* __restrict__ r, const float* __restrict__ ologp,
    const float* __restrict__ tlogp, unsigned* __restrict__ pkPre,
    float* __restrict__ P, float* __restrict__ Zl) {
  const int chunk = blockIdx.x >> 3;  // 0..MCH-1
  const int k = (blockIdx.x & 7) * 256 + threadIdx.x;
  const int i0 = chunk * L_;

  float lw[L_], a[L_], v[L_], rr[L_], o[L_];
#pragma unroll
  for (int s = 0; s < L_; ++s) {  // all loads independent -> MLP
    const int i = i0 + s;
    const size_t b1 = (size_t)(i + 1) * K_ + k;
    lw[s] = tlogp[b1];
    a[s] = tsv[b1];
    v[s] = tev[b1];
    rr[s] = r[(size_t)i * K_ + k];
    o[s] = ologp[i + 1];  // block-uniform -> scalar load
  }
  float p = 1.f, zl = 0.f;
#pragma unroll
  for (int s = 0; s < L_; ++s) {
    float iw = __expf(fminf(lw[s] - o[s], 0.f));
    float c = GAMMA * iw;
    p *= c;
    float td = fmaf(GAMMA, fmaf(-iw, a[s], v[s]), rr[s]);
    float tdb = bf2f(f2bf(td));  // bf16 round-trip (proven path)
    float y = tdb * p;
    zl += y;
    pkPre[(size_t)(i0 + s) * K_ + k] = ((unsigned)f2bf(y) << 16) | f2bf(p);
  }
  P[(size_t)chunk * K_ + k] = p;
  Zl[(size_t)chunk * K_ + k] = zl;
}

// ---------------------------------------------------------------- kApply
// Role A: prefix apply with inline chunk scan over P/Zl (L2-hot;
//   forward-order ssuf accumulation proven R7/R12, absmax 0.0).
// Role B: tail sl1(sv) unconditional, rolled grid-stride loop (R13 form;
//   R15 proved deep batching is null -- BW ceiling, not latency).
// Role C: inline alive check; exact serial fallback per alive column,
//   subtracting role B's assumed terms (never taken for this data).
// Every block writes its own partials slot. NO atomics, NO fences.
__global__ __launch_bounds__(256) void kApply(
    const float* __restrict__ sv, const float* __restrict__ tsv,
    const float* __restrict__ tev, const float* __restrict__ r,
    const float* __restrict__ ologp, const float* __restrict__ tlogp,
    const unsigned* __restrict__ pkPre, const float* __restrict__ P,
    const float* __restrict__ Zl, unsigned* __restrict__ pkFull,
    float* __restrict__ partials) {
  const int bid = blockIdx.x;
  const int tid = threadIdx.x;

  if (bid < NBPRE) {  // ---- role A: prefix rows [0,MROWS)
    const int myc = bid >> 3;
    const int k = (bid & 7) * 256 + tid;
    float d0 = 1.f, dj = 1.f;
#pragma unroll 8
    for (int c = 0; c < MCH; ++c) {
      if (c == myc) d0 = dj;
      dj *= P[(size_t)c * K_ + k];
    }
    float loss = 0.f;
    if (dj == 0.f) {  // dead column (typical): chunked result is exact
      float ssuf = 0.f;
      float dp = d0 * P[(size_t)myc * K_ + k];
      for (int c = myc + 1; c < MCH; ++c) {
        ssuf = fmaf(dp, Zl[(size_t)c * K_ + k], ssuf);
        dp *= P[(size_t)c * K_ + k];
      }
      const int i0 = myc * L_;
      unsigned q[L_];
      float svv[L_];
#pragma unroll
      for (int s = 0; s < L_; ++s) {  // batch loads before the chain
        const size_t b0 = (size_t)(i0 + s) * K_ + k;
        q[s] = pkPre[b0];
        svv[s] = sv[b0];
      }
      float slocal = 0.f;
#pragma unroll
      for (int s = L_ - 1; s >= 0; --s) {
        slocal += bfhi(q[s]);
        float S = fmaf(d0, slocal, ssuf);
        float retrace = S / fmaxf(d0 * bflo(q[s]), 1e-10f);
        loss += sl1(svv[s] - retrace);
      }
    }
    block_reduce_store(loss, partials + bid);
  } else if (bid < NBPRE + NBTAIL) {  // ---- role B: tail, rolled loop
    const long long base = (long long)MROWS * K_ / 4;  // f4 offset
    float loss = 0.f;
    for (long long v = (long long)(bid - NBPRE) * 256 + tid; v < TAILF4;
         v += (long long)NBTAIL * 256) {
      f4 q = ((const f4*)sv)[base + v];
#pragma unroll
      for (int x = 0; x < 4; ++x) loss += sl1(q[x]);
    }
    block_reduce_store(loss, partials + bid);
  } else {  // ---- role C: thread per column; inline alive check
    const int k = (bid - NBPRE - NBTAIL) * 256 + tid;
    float loss = 0.f;
    float dj = 1.f;
#pragma unroll 8
    for (int c = 0; c < MCH; ++c) dj *= P[(size_t)c * K_ + k];
    if (dj != 0.f) {  // alive (never for this data): exact recompute
      unsigned* mycol = pkFull + (size_t)k * 8192;
      float p = 1.f;
      for (int i = 0; i < N_; ++i) {  // forward: exact sequential decay
        const size_t b1 = (size_t)(i + 1) * K_ + k;
        float iw = __expf(fminf(tlogp[b1] - ologp[i + 1], 0.f));
        p *= GAMMA * iw;
        float td =
            fmaf(GAMMA, fmaf(-iw, tsv[b1], tev[b1]), r[(size_t)i * K_ + k]);
        mycol[i] = ((unsigned)f2bf(td * p) << 16) | f2bf(p);
      }
      float slocal = 0.f;
      for (int i = N_ - 1; i >= 0; --i) {  // backward: S, loss, tail undo
        unsigned q = mycol[i];
        slocal += bfhi(q);
        float retrace = slocal / fmaxf(bflo(q), 1e-10f);
        float qv = sv[(size_t)i * K_ + k];
        loss += sl1(qv - retrace);
        if (i >= MROWS) loss -= sl1(qv);  // role B added this for ALL cols
      }
      // role A contributed 0 for alive columns (dj != 0 skip) -> no dup.
    }
    block_reduce_store(loss, partials + bid);
  }
}

// ---------------------------------------------------------------- k4
// Single block: f64 sum of the 2376 per-block partials, write mean.
__global__ __launch_bounds__(256) void k4(const float* __restrict__ partials,
                                          float* __restrict__ out) {
  double d = 0.0;
  for (int i = threadIdx.x; i < NBTOT; i += 256) d += (double)partials[i];
  for (int off = 32; off > 0; off >>= 1) d += __shfl_down(d, off);
  __shared__ double wsum[4];
  const int lane = threadIdx.x & 63, wid = threadIdx.x >> 6;
  if (lane == 0) wsum[wid] = d;
  __syncthreads();
  if (threadIdx.x == 0) {
    double s = wsum[0] + wsum[1] + wsum[2] + wsum[3];
    out[0] = (float)(s * (1.0 / ((double)N_ * (double)K_)));
  }
}

extern "C" void kernel_launch(void* const* d_in, const int* in_sizes, int n_in,
                              void* d_out, int out_size, void* d_ws,
                              size_t ws_size, hipStream_t stream) {
  const float* sv = (const float*)d_in[0];
  const float* tsv = (const float*)d_in[1];
  const float* tev = (const float*)d_in[2];
  const float* r = (const float*)d_in[3];
  const float* ologp = (const float*)d_in[4];
  const float* tlogp = (const float*)d_in[5];

  // ws layout (~70 MB; harness provided >= 75.5 MB rounds 2-15).
  // partials on its own page (R9 lesson: no ctrl-line sharing).
  char* w = (char*)d_ws;
  float* partials = (float*)w;  // 2376 f32, page 0
  w += 16384;
  unsigned* pkPre = (unsigned*)w;  // 320*2048*4 = 2.6 MB
  w += (size_t)MROWS * K_ * 4;
  float* P = (float*)w;  // 40*2048*4 = 327 KB each
  w += (size_t)MCH * K_ * 4;
  float* Zl = (float*)w;
  w += (size_t)MCH * K_ * 4;
  unsigned* pkFull = (unsigned*)w;  // 67 MB (role-C fallback only)

  kPre<<<NBPRE, 256, 0, stream>>>(tsv, tev, r, ologp, tlogp, pkPre, P, Zl);
  kApply<<<NBTOT, 256, 0, stream>>>(sv, tsv, tev, r, ologp, tlogp, pkPre, P,
                                    Zl, pkFull, partials);
  k4<<<1, 256, 0, stream>>>(partials, (float*)d_out);
}